// Round 10
// baseline (115.239 us; speedup 1.0000x reference)
//
#include <hip/hip_runtime.h>
#include <hip/hip_bf16.h>
#include <cstdint>
#include <cstddef>

#define B_   2
#define H_   12
#define T_   2048
#define C_   768
#define HD_  64
#define M_   4096      // B_*T_
#define NW_  (T_/64)   // 32 mask words per row
#define NPAIR 2        // wave-pairs per block (split-K)

typedef __attribute__((ext_vector_type(8))) short bf16x8;
typedef __attribute__((ext_vector_type(4))) float fx4;
typedef __attribute__((ext_vector_type(16))) float f32x16;
typedef unsigned short u16;
typedef unsigned int   u32;
typedef unsigned long long u64;

static __device__ __forceinline__ u16 f2bf(float f){
    union { float f; unsigned int i; } c; c.f = f;
    unsigned int x = c.i;
    return (u16)((x + 0x7fffu + ((x >> 16) & 1u)) >> 16);  // RNE
}

static __device__ __forceinline__ u32 pack_bf2(float a, float b){
    union { __hip_bfloat162 h; u32 u; } cv;
    cv.h = __float22bfloat162_rn(make_float2(a, b));   // [15:0]=a, [31:16]=b
    return cv.u;
}

// ---------------- fused prep: x->bf16, weights->bf16 (concat), mask->bits ----------------
#define PREP_XBLK (M_ * C_ / 4 / 256)       // 3072
#define PREP_WBLK (4 * C_ * C_ / 4 / 256)   // 2304
#define PREP_MBLK (B_ * T_ * NW_ / 4)       // 32768
__global__ void prep(const float* __restrict__ x,
                     const float* __restrict__ wq, const float* __restrict__ wk,
                     const float* __restrict__ wv, const float* __restrict__ wp,
                     const float* __restrict__ mask,
                     u16* __restrict__ xb, u16* __restrict__ wqkv, u64* __restrict__ bits)
{
    int bx = blockIdx.x;
    if (bx < PREP_XBLK){
        int i = bx * 256 + threadIdx.x;
        float4 v = ((const float4*)x)[i];
        ushort4 o;
        o.x = f2bf(v.x); o.y = f2bf(v.y); o.z = f2bf(v.z); o.w = f2bf(v.w);
        ((ushort4*)xb)[i] = o;
    } else if (bx < PREP_XBLK + PREP_WBLK){
        int i = (bx - PREP_XBLK) * 256 + threadIdx.x;
        int wsel = i / (C_ * C_ / 4);
        int wi   = i % (C_ * C_ / 4);
        const float* src = (wsel == 0) ? wq : (wsel == 1) ? wk : (wsel == 2) ? wv : wp;
        float4 v = ((const float4*)src)[wi];
        ushort4 o;
        o.x = f2bf(v.x); o.y = f2bf(v.y); o.z = f2bf(v.z); o.w = f2bf(v.w);
        ((ushort4*)wqkv)[i] = o;
    } else {
        int wid  = (bx - PREP_XBLK - PREP_WBLK) * 4 + (threadIdx.x >> 6);
        int lane = threadIdx.x & 63;
        float v = mask[(size_t)wid * 64 + lane];
        u64 m = __ballot(v > 0.0f);
        if (lane == 0) bits[wid] = m;
    }
}

// ---------------- fused QKV GEMM, BK=64, 2-phase double-buffered pipeline ----------------
__launch_bounds__(256)
__global__ void gemm_qkv(const u16* __restrict__ xb, const u16* __restrict__ wqkv,
                         const float* __restrict__ bq, const float* __restrict__ bk,
                         const float* __restrict__ bv,
                         u16* __restrict__ qo, u16* __restrict__ ko, u16* __restrict__ vto)
{
    const int tid  = threadIdx.x;
    const int lane = tid & 63, wave = tid >> 6;
    const int l15 = lane & 15, lg = lane >> 4;
    // XCD swizzle: nwg = 6*32*3 = 576, 576%8==0
    int flat = blockIdx.x + 6 * (blockIdx.y + 32 * blockIdx.z);
    int swz  = (flat & 7) * 72 + (flat >> 3);
    const int n0 = (swz % 6) * 128;
    const int m0 = ((swz / 6) % 32) * 128;
    const int z  = swz / 192;
    const u16* wb     = wqkv + (size_t)z * C_ * C_;
    const float* bias = (z == 0) ? bq : (z == 1 ? bk : bv);
    const float oscl  = (z == 0) ? 0.1803368801111601f : 1.0f;  // 0.125*log2(e)

    __shared__ __align__(16) u16 lds_a[2][128 * 64];
    __shared__ __align__(16) u16 lds_b[2][128 * 64];

    fx4 acc[4][4];
    #pragma unroll
    for (int i = 0; i < 4; i++)
        #pragma unroll
        for (int j = 0; j < 4; j++) acc[i][j] = (fx4)0.0f;

    const int wm = (wave >> 1) * 64, wn = (wave & 1) * 64;
    const int sx = l15 & 7;
    const int NT = C_ / 64;   // 12

    auto stage = [&](int buf, int kt){
        const int k0 = kt * 64;
        #pragma unroll
        for (int c = 0; c < 4; ++c){
            int unit = c * 256 + tid;
            int row = unit >> 3, col = unit & 7;
            int gcol = (col ^ (row & 7)) * 8;
            const u16* ga = xb + (size_t)(m0 + row) * C_ + k0 + gcol;
            __builtin_amdgcn_global_load_lds((const __attribute__((address_space(1))) void*)ga,
                (__attribute__((address_space(3))) void*)(&lds_a[buf][(c * 256 + wave * 64) * 8]), 16, 0, 0);
            const u16* gb = wb + (size_t)(n0 + row) * C_ + k0 + gcol;
            __builtin_amdgcn_global_load_lds((const __attribute__((address_space(1))) void*)gb,
                (__attribute__((address_space(3))) void*)(&lds_b[buf][(c * 256 + wave * 64) * 8]), 16, 0, 0);
        }
    };

    stage(0, 0);
    __syncthreads();
    int cur = 0;
    for (int kt = 0; kt < NT; ++kt){
        if (kt + 1 < NT) stage(cur ^ 1, kt + 1);   // next tile flies under compute
        #pragma unroll
        for (int ks = 0; ks < 2; ++ks){
            bf16x8 af[4], bfr[4];
            #pragma unroll
            for (int i = 0; i < 4; i++){
                af[i]  = *(const bf16x8*)&lds_a[cur][(wm + i * 16 + l15) * 64 + (((4 * ks + lg) ^ sx) * 8)];
                bfr[i] = *(const bf16x8*)&lds_b[cur][(wn + i * 16 + l15) * 64 + (((4 * ks + lg) ^ sx) * 8)];
            }
            #pragma unroll
            for (int i = 0; i < 4; i++)
                #pragma unroll
                for (int j = 0; j < 4; j++)
                    acc[i][j] = __builtin_amdgcn_mfma_f32_16x16x32_bf16(af[i], bfr[j], acc[i][j], 0, 0, 0);
        }
        __syncthreads();    // implicit vmcnt(0): next tile landed; buf[cur] free to overwrite
        cur ^= 1;
    }

    #pragma unroll
    for (int i = 0; i < 4; i++){
        #pragma unroll
        for (int j = 0; j < 4; j++){
            #pragma unroll
            for (int r = 0; r < 4; r++){
                int m = m0 + wm + i * 16 + lg * 4 + r;
                int n = n0 + wn + j * 16 + l15;
                float v = (acc[i][j][r] + bias[n]) * oscl;
                u16 o = f2bf(v);
                int b = m >> 11, t = m & (T_ - 1);
                int h = n >> 6, d = n & 63;
                if (z == 2){
                    vto[(size_t)((b * H_ + h) * HD_ + d) * T_ + t] = o;
                } else {
                    u16* dst = (z == 0) ? qo : ko;
                    dst[(size_t)((b * H_ + h) * T_ + t) * HD_ + d] = o;
                }
            }
        }
    }
}

// ---------------- output projection GEMM (fp32 out), 2-phase double-buffered ----------------
__launch_bounds__(256)
__global__ void gemm_proj(const u16* __restrict__ yb, const u16* __restrict__ wp,
                          const float* __restrict__ bp, float* __restrict__ out)
{
    const int tid  = threadIdx.x;
    const int lane = tid & 63, wave = tid >> 6;
    const int l15 = lane & 15, lg = lane >> 4;
    // XCD swizzle: nwg = 192
    int flat = blockIdx.x + 6 * blockIdx.y;
    int swz  = (flat & 7) * 24 + (flat >> 3);
    const int n0 = (swz % 6) * 128;
    const int m0 = (swz / 6) * 128;

    __shared__ __align__(16) u16 lds_a[2][128 * 64];
    __shared__ __align__(16) u16 lds_b[2][128 * 64];

    fx4 acc[4][4];
    #pragma unroll
    for (int i = 0; i < 4; i++)
        #pragma unroll
        for (int j = 0; j < 4; j++) acc[i][j] = (fx4)0.0f;

    const int wm = (wave >> 1) * 64, wn = (wave & 1) * 64;
    const int sx = l15 & 7;
    const int NT = C_ / 64;

    auto stage = [&](int buf, int kt){
        const int k0 = kt * 64;
        #pragma unroll
        for (int c = 0; c < 4; ++c){
            int unit = c * 256 + tid;
            int row = unit >> 3, col = unit & 7;
            int gcol = (col ^ (row & 7)) * 8;
            const u16* ga = yb + (size_t)(m0 + row) * C_ + k0 + gcol;
            __builtin_amdgcn_global_load_lds((const __attribute__((address_space(1))) void*)ga,
                (__attribute__((address_space(3))) void*)(&lds_a[buf][(c * 256 + wave * 64) * 8]), 16, 0, 0);
            const u16* gb = wp + (size_t)(n0 + row) * C_ + k0 + gcol;
            __builtin_amdgcn_global_load_lds((const __attribute__((address_space(1))) void*)gb,
                (__attribute__((address_space(3))) void*)(&lds_b[buf][(c * 256 + wave * 64) * 8]), 16, 0, 0);
        }
    };

    stage(0, 0);
    __syncthreads();
    int cur = 0;
    for (int kt = 0; kt < NT; ++kt){
        if (kt + 1 < NT) stage(cur ^ 1, kt + 1);
        #pragma unroll
        for (int ks = 0; ks < 2; ++ks){
            bf16x8 af[4], bfr[4];
            #pragma unroll
            for (int i = 0; i < 4; i++){
                af[i]  = *(const bf16x8*)&lds_a[cur][(wm + i * 16 + l15) * 64 + (((4 * ks + lg) ^ sx) * 8)];
                bfr[i] = *(const bf16x8*)&lds_b[cur][(wn + i * 16 + l15) * 64 + (((4 * ks + lg) ^ sx) * 8)];
            }
            #pragma unroll
            for (int i = 0; i < 4; i++)
                #pragma unroll
                for (int j = 0; j < 4; j++)
                    acc[i][j] = __builtin_amdgcn_mfma_f32_16x16x32_bf16(af[i], bfr[j], acc[i][j], 0, 0, 0);
        }
        __syncthreads();
        cur ^= 1;
    }

    #pragma unroll
    for (int i = 0; i < 4; i++)
        #pragma unroll
        for (int j = 0; j < 4; j++)
            #pragma unroll
            for (int r = 0; r < 4; r++){
                int m = m0 + wm + i * 16 + lg * 4 + r;
                int n = n0 + wn + j * 16 + l15;
                out[(size_t)m * C_ + n] = acc[i][j][r] + bp[n];
            }
}

// ---------------- flash attention: 2-way split-K, 256 threads, 32KB LDS ----------------
// (unchanged from round 9)
__launch_bounds__(256)
__global__ void attn(const u16* __restrict__ q, const u16* __restrict__ kmat,
                     const u16* __restrict__ vt, const u64* __restrict__ bits,
                     u16* __restrict__ y)
{
    const int tid = threadIdx.x;
    const int pr  = tid >> 7;            // pair 0..1
    const int ptid = tid & 127;
    const int w2  = (tid >> 6) & 1;      // q-half within pair
    const int lane = tid & 63;
    const int l31 = lane & 31, hi = lane >> 5;

    int flat = blockIdx.x;
    const int bh = (flat & 7) * 3 + ((flat >> 3) % 3);     // 3 heads per XCD
    const int qt = 31 - (flat >> 3) / 3;                   // heavy first
    const int b = bh / H_, h = bh % H_;
    const int qw0 = qt * 64 + 32 * w2;

    extern __shared__ __align__(16) u16 smem[];     // 32KB: [pair][K 8KB | V 8KB]
    u16* lds_k = smem + (size_t)pr * 8192;          // [64][64] swizzled (granule ^= row&7)
    u16* lds_v = lds_k + 4096;                      // [64][64] swizzled
    float* lds_ml = (float*)smem;                   // merge m/l, aliases pair0 region

    const size_t bhoff = (size_t)bh * T_ * HD_;
    const u16* kb_ = kmat + bhoff;
    const u16* vb_ = vt + bhoff;

    bf16x8 qf[4];
    {
        const u16* qrow = q + bhoff + (size_t)(qw0 + l31) * HD_ + hi * 8;
        #pragma unroll
        for (int dc = 0; dc < 4; dc++)
            qf[dc] = *(const bf16x8*)(qrow + dc * 16);
    }

    f32x16 o0 = (f32x16)0.0f, o1 = (f32x16)0.0f;
    float m_l = -1e30f, l_l = 0.0f;            // per lane, q = qw0 + l31

    const int nkt = qt + 1;
    const int nit = (nkt + NPAIR - 1) / NPAIR;
    const int qg  = qw0 + l31;
    const u64* brow = bits + (size_t)(b * T_ + qg) * NW_;

    for (int it = 0; it < nit; ++it){
        const int kt = it * NPAIR + pr;
        const bool valid = kt < nkt;
        const int kbase = kt * 64;

        if (it > 0) __syncthreads();
        if (valid){
            #pragma unroll
            for (int i = 0; i < 4; i++){
                int u = i * 128 + ptid;    // 16B unit
                int row = u >> 3, col = u & 7;
                int gcol = (col ^ (row & 7)) * 8;
                __builtin_amdgcn_global_load_lds(
                    (const __attribute__((address_space(1))) void*)(kb_ + (size_t)(kbase + row) * HD_ + gcol),
                    (__attribute__((address_space(3))) void*)(lds_k + u * 8), 16, 0, 0);
                __builtin_amdgcn_global_load_lds(
                    (const __attribute__((address_space(1))) void*)(vb_ + (size_t)row * T_ + kbase + gcol),
                    (__attribute__((address_space(3))) void*)(lds_v + u * 8), 16, 0, 0);
            }
        }
        __syncthreads();

        if (valid){
            f32x16 s0 = (f32x16)0.0f, s1 = (f32x16)0.0f;
            #pragma unroll
            for (int dc = 0; dc < 4; dc++){
                bf16x8 kf0 = *(const bf16x8*)&lds_k[(l31     ) * 64 + (((2 * dc + hi) ^ (l31 & 7)) * 8)];
                bf16x8 kf1 = *(const bf16x8*)&lds_k[(l31 + 32) * 64 + (((2 * dc + hi) ^ (l31 & 7)) * 8)];
                s0 = __builtin_amdgcn_mfma_f32_32x32x16_bf16(kf0, qf[dc], s0, 0, 0, 0);
                s1 = __builtin_amdgcn_mfma_f32_32x32x16_bf16(kf1, qf[dc], s1, 0, 0, 0);
            }

            u64 raw = brow[kt];
            int sh = qg - kbase;
            u64 vis = sh < 0 ? 0ull : (sh >= 63 ? ~0ull : ((2ull << sh) - 1ull));
            u64 masked = raw & vis;
            if (!__all(masked == ~0ull)){
                u32 mk0 = (u32)(masked >> (4 * hi));
                u32 mk1 = (u32)(masked >> (32 + 4 * hi));
                #pragma unroll
                for (int r = 0; r < 16; r++){
                    int bpos = (r & 3) + 8 * (r >> 2);
                    s0[r] = ((mk0 >> bpos) & 1u) ? s0[r] : -1e30f;
                    s1[r] = ((mk1 >> bpos) & 1u) ? s1[r] : -1e30f;
                }
            }

            float mx = -1e30f;
            #pragma unroll
            for (int r = 0; r < 16; r++){ mx = fmaxf(mx, s0[r]); mx = fmaxf(mx, s1[r]); }
            mx = fmaxf(mx, __shfl_xor(mx, 32, 64));

            if (!__all(mx <= m_l + 10.0f)){
                float mnew = fmaxf(m_l, mx);
                float al = __builtin_amdgcn_exp2f(m_l - mnew);
                m_l = mnew;
                l_l *= al;
                #pragma unroll
                for (int r = 0; r < 16; r++){
                    int ql = (r & 3) + 8 * (r >> 2) + 4 * hi;
                    float a_r = __shfl(al, ql, 64);
                    o0[r] *= a_r; o1[r] *= a_r;
                }
            }

            float rs = 0.0f;
            bf16x8 pa[2][2];
            #pragma unroll
            for (int kb = 0; kb < 2; kb++){
                u32 P[8];
                #pragma unroll
                for (int g = 0; g < 8; g++){
                    float pe0 = __builtin_amdgcn_exp2f((kb ? s1[2*g]   : s0[2*g])   - m_l);
                    float pe1 = __builtin_amdgcn_exp2f((kb ? s1[2*g+1] : s0[2*g+1]) - m_l);
                    rs += pe0 + pe1;
                    P[g] = pack_bf2(pe0, pe1);
                }
                asm volatile("v_permlane32_swap_b32 %0, %1" : "+v"(P[0]), "+v"(P[2]));
                asm volatile("v_permlane32_swap_b32 %0, %1" : "+v"(P[1]), "+v"(P[3]));
                asm volatile("v_permlane32_swap_b32 %0, %1" : "+v"(P[4]), "+v"(P[6]));
                asm volatile("v_permlane32_swap_b32 %0, %1" : "+v"(P[5]), "+v"(P[7]));
                union { u32 uw[4]; bf16x8 v; } u0, u1;
                u0.uw[0]=P[0]; u0.uw[1]=P[1]; u0.uw[2]=P[2]; u0.uw[3]=P[3];
                u1.uw[0]=P[4]; u1.uw[1]=P[5]; u1.uw[2]=P[6]; u1.uw[3]=P[7];
                pa[kb][0] = u0.v; pa[kb][1] = u1.v;
            }
            rs += __shfl_xor(rs, 32, 64);
            l_l += rs;

            #pragma unroll
            for (int kb = 0; kb < 2; kb++)
                #pragma unroll
                for (int ks = 0; ks < 2; ks++){
                    int gidx = 4 * kb + 2 * ks + hi;
                    bf16x8 vf0 = *(const bf16x8*)&lds_v[(l31     ) * 64 + ((gidx ^ (l31 & 7)) * 8)];
                    bf16x8 vf1 = *(const bf16x8*)&lds_v[(l31 + 32) * 64 + ((gidx ^ (l31 & 7)) * 8)];
                    o0 = __builtin_amdgcn_mfma_f32_32x32x16_bf16(pa[kb][ks], vf0, o0, 0, 0, 0);
                    o1 = __builtin_amdgcn_mfma_f32_32x32x16_bf16(pa[kb][ks], vf1, o1, 0, 0, 0);
                }
        }
    }

    __syncthreads();
    {
        const int qrow = w2 * 32 + l31;
        if (hi == 0){
            lds_ml[(pr * 2 + 0) * 64 + qrow] = m_l;
            lds_ml[(pr * 2 + 1) * 64 + qrow] = l_l;
        }
        if (pr != 0){
            float* Od = (float*)(smem + (size_t)pr * 8192);
            #pragma unroll
            for (int r = 0; r < 16; r++){
                int ql = (r & 3) + 8 * (r >> 2) + 4 * hi;
                int row = w2 * 32 + ql;
                Od[row * 64 + l31]      = o0[r];
                Od[row * 64 + 32 + l31] = o1[r];
            }
        }
    }
    __syncthreads();

    if (pr == 0){
        const int qrow = w2 * 32 + l31;
        float mvals[NPAIR], lvals[NPAIR];
        mvals[0] = m_l; lvals[0] = l_l;
        #pragma unroll
        for (int p = 1; p < NPAIR; p++){
            mvals[p] = lds_ml[(p * 2 + 0) * 64 + qrow];
            lvals[p] = lds_ml[(p * 2 + 1) * 64 + qrow];
        }
        float mm = mvals[0];
        #pragma unroll
        for (int p = 1; p < NPAIR; p++) mm = fmaxf(mm, mvals[p]);
        float a[NPAIR], ltot = 0.0f;
        #pragma unroll
        for (int p = 0; p < NPAIR; p++){
            a[p] = __builtin_amdgcn_exp2f(mvals[p] - mm);
            ltot += lvals[p] * a[p];
        }
        float inv = 1.0f / ltot;

        #pragma unroll
        for (int r = 0; r < 16; r++){
            int ql = (r & 3) + 8 * (r >> 2) + 4 * hi;
            int row = w2 * 32 + ql;
            float a0r = __shfl(a[0], ql, 64);
            float v0 = o0[r] * a0r;
            float v1 = o1[r] * a0r;
            #pragma unroll
            for (int p = 1; p < NPAIR; p++){
                float apr = __shfl(a[p], ql, 64);
                const float* Od = (const float*)(smem + (size_t)p * 8192);
                v0 += Od[row * 64 + l31]      * apr;
                v1 += Od[row * 64 + 32 + l31] * apr;
            }
            float ivr = __shfl(inv, ql, 64);
            int trow = qt * 64 + row;
            u16* yr = y + (size_t)(b * T_ + trow) * C_ + h * HD_;
            yr[l31]      = f2bf(v0 * ivr);
            yr[32 + l31] = f2bf(v1 * ivr);
        }
    }
}

extern "C" void kernel_launch(void* const* d_in, const int* in_sizes, int n_in,
                              void* d_out, int out_size, void* d_ws, size_t ws_size,
                              hipStream_t stream)
{
    const float* x    = (const float*)d_in[0];
    const float* mask = (const float*)d_in[1];
    const float* Wq   = (const float*)d_in[2];
    const float* bq   = (const float*)d_in[3];
    const float* Wk   = (const float*)d_in[4];
    const float* bk   = (const float*)d_in[5];
    const float* Wv   = (const float*)d_in[6];
    const float* bv   = (const float*)d_in[7];
    const float* Wp   = (const float*)d_in[8];
    const float* bp   = (const float*)d_in[9];
    float* out = (float*)d_out;

    char* p = (char*)d_ws;
    u16* xb   = (u16*)p; p += (size_t)M_ * C_ * 2;
    u16* wqkv = (u16*)p; p += (size_t)4 * C_ * C_ * 2;
    u16* qo   = (u16*)p; p += (size_t)M_ * C_ * 2;       // [B,H,T,64] (pre-scaled)
    u16* ko   = (u16*)p; p += (size_t)M_ * C_ * 2;       // [B,H,T,64]
    u16* vto  = (u16*)p; p += (size_t)M_ * C_ * 2;       // [B,H,64,T]
    u16* yb   = (u16*)p; p += (size_t)M_ * C_ * 2;       // attn out bf16
    u64* bits = (u64*)p; p += (size_t)B_ * T_ * NW_ * 8;

    prep<<<dim3(PREP_XBLK + PREP_WBLK + PREP_MBLK), 256, 0, stream>>>(
        x, Wq, Wk, Wv, Wp, mask, xb, wqkv, bits);

    gemm_qkv<<<dim3(C_ / 128, M_ / 128, 3), 256, 0, stream>>>(
        xb, wqkv, bq, bk, bv, qo, ko, vto);

    attn<<<dim3((T_ / 64) * B_ * H_), 256, NPAIR * 8192 * sizeof(u16), stream>>>(
        qo, ko, vto, bits, yb);

    gemm_proj<<<dim3(C_ / 128, M_ / 128), 256, 0, stream>>>(yb, wqkv + (size_t)3 * C_ * C_, bp, out);
}

// Round 11
// 109.219 us; speedup vs baseline: 1.0551x; 1.0551x over previous
//
#include <hip/hip_runtime.h>
#include <hip/hip_bf16.h>
#include <cstdint>
#include <cstddef>

#define B_   2
#define H_   12
#define T_   2048
#define C_   768
#define HD_  64
#define M_   4096      // B_*T_
#define NW_  (T_/64)   // 32 mask words per row
#define NPAIR 2        // wave-pairs per block (split-K)

typedef __attribute__((ext_vector_type(8))) short bf16x8;
typedef __attribute__((ext_vector_type(4))) float fx4;
typedef __attribute__((ext_vector_type(16))) float f32x16;
typedef unsigned short u16;
typedef unsigned int   u32;
typedef unsigned long long u64;

static __device__ __forceinline__ u16 f2bf(float f){
    union { float f; unsigned int i; } c; c.f = f;
    unsigned int x = c.i;
    return (u16)((x + 0x7fffu + ((x >> 16) & 1u)) >> 16);  // RNE
}

static __device__ __forceinline__ u32 pack_bf2(float a, float b){
    union { __hip_bfloat162 h; u32 u; } cv;
    cv.h = __float22bfloat162_rn(make_float2(a, b));   // [15:0]=a, [31:16]=b
    return cv.u;
}

// ---------------- fused prep: x->bf16, weights->bf16 (concat), mask->bits ----------------
#define PREP_XBLK (M_ * C_ / 4 / 256)       // 3072
#define PREP_WBLK (4 * C_ * C_ / 4 / 256)   // 2304
#define PREP_MBLK (B_ * T_ * NW_ / 4)       // 32768
__global__ void prep(const float* __restrict__ x,
                     const float* __restrict__ wq, const float* __restrict__ wk,
                     const float* __restrict__ wv, const float* __restrict__ wp,
                     const float* __restrict__ mask,
                     u16* __restrict__ xb, u16* __restrict__ wqkv, u64* __restrict__ bits)
{
    int bx = blockIdx.x;
    if (bx < PREP_XBLK){
        int i = bx * 256 + threadIdx.x;
        float4 v = ((const float4*)x)[i];
        ushort4 o;
        o.x = f2bf(v.x); o.y = f2bf(v.y); o.z = f2bf(v.z); o.w = f2bf(v.w);
        ((ushort4*)xb)[i] = o;
    } else if (bx < PREP_XBLK + PREP_WBLK){
        int i = (bx - PREP_XBLK) * 256 + threadIdx.x;
        int wsel = i / (C_ * C_ / 4);
        int wi   = i % (C_ * C_ / 4);
        const float* src = (wsel == 0) ? wq : (wsel == 1) ? wk : (wsel == 2) ? wv : wp;
        float4 v = ((const float4*)src)[wi];
        ushort4 o;
        o.x = f2bf(v.x); o.y = f2bf(v.y); o.z = f2bf(v.z); o.w = f2bf(v.w);
        ((ushort4*)wqkv)[i] = o;
    } else {
        int wid  = (bx - PREP_XBLK - PREP_WBLK) * 4 + (threadIdx.x >> 6);
        int lane = threadIdx.x & 63;
        float v = mask[(size_t)wid * 64 + lane];
        u64 m = __ballot(v > 0.0f);
        if (lane == 0) bits[wid] = m;
    }
}

// ---------------- fused QKV GEMM: 64x128 tile, BK=64, single-buffer, 1152 blocks ----------------
__launch_bounds__(256)
__global__ void gemm_qkv(const u16* __restrict__ xb, const u16* __restrict__ wqkv,
                         const float* __restrict__ bq, const float* __restrict__ bk,
                         const float* __restrict__ bv,
                         u16* __restrict__ qo, u16* __restrict__ ko, u16* __restrict__ vto)
{
    const int tid  = threadIdx.x;
    const int lane = tid & 63, wave = tid >> 6;
    const int l15 = lane & 15, lg = lane >> 4;
    // XCD swizzle: nwg = 6*64*3 = 1152, 1152/8 = 144
    int flat = blockIdx.x + 6 * (blockIdx.y + 64 * blockIdx.z);
    int swz  = (flat & 7) * 144 + (flat >> 3);
    const int n0 = (swz % 6) * 128;
    const int m0 = ((swz / 6) % 64) * 64;
    const int z  = swz / 384;
    const u16* wb     = wqkv + (size_t)z * C_ * C_;
    const float* bias = (z == 0) ? bq : (z == 1 ? bk : bv);
    const float oscl  = (z == 0) ? 0.1803368801111601f : 1.0f;  // 0.125*log2(e)

    __shared__ __align__(16) u16 lds_a[64 * 64];    // 8 KB
    __shared__ __align__(16) u16 lds_b[128 * 64];   // 16 KB

    fx4 acc[2][4];
    #pragma unroll
    for (int i = 0; i < 2; i++)
        #pragma unroll
        for (int j = 0; j < 4; j++) acc[i][j] = (fx4)0.0f;

    const int wm = (wave >> 1) * 32, wn = (wave & 1) * 64;
    const int sx = l15 & 7;

    for (int kt = 0; kt < C_ / 64; ++kt){
        const int k0 = kt * 64;
        #pragma unroll
        for (int c = 0; c < 2; ++c){   // A: 512 units
            int unit = c * 256 + tid;
            int row = unit >> 3, col = unit & 7;
            int gcol = (col ^ (row & 7)) * 8;
            const u16* ga = xb + (size_t)(m0 + row) * C_ + k0 + gcol;
            __builtin_amdgcn_global_load_lds((const __attribute__((address_space(1))) void*)ga,
                (__attribute__((address_space(3))) void*)(lds_a + unit * 8), 16, 0, 0);
        }
        #pragma unroll
        for (int c = 0; c < 4; ++c){   // B: 1024 units
            int unit = c * 256 + tid;
            int row = unit >> 3, col = unit & 7;
            int gcol = (col ^ (row & 7)) * 8;
            const u16* gb = wb + (size_t)(n0 + row) * C_ + k0 + gcol;
            __builtin_amdgcn_global_load_lds((const __attribute__((address_space(1))) void*)gb,
                (__attribute__((address_space(3))) void*)(lds_b + unit * 8), 16, 0, 0);
        }
        __syncthreads();
        #pragma unroll
        for (int ks = 0; ks < 2; ++ks){
            bf16x8 af[2], bfr[4];
            #pragma unroll
            for (int i = 0; i < 2; i++)
                af[i]  = *(const bf16x8*)&lds_a[(wm + i * 16 + l15) * 64 + (((4 * ks + lg) ^ sx) * 8)];
            #pragma unroll
            for (int j = 0; j < 4; j++)
                bfr[j] = *(const bf16x8*)&lds_b[(wn + j * 16 + l15) * 64 + (((4 * ks + lg) ^ sx) * 8)];
            #pragma unroll
            for (int i = 0; i < 2; i++)
                #pragma unroll
                for (int j = 0; j < 4; j++)
                    acc[i][j] = __builtin_amdgcn_mfma_f32_16x16x32_bf16(af[i], bfr[j], acc[i][j], 0, 0, 0);
        }
        __syncthreads();
    }

    #pragma unroll
    for (int i = 0; i < 2; i++){
        #pragma unroll
        for (int j = 0; j < 4; j++){
            #pragma unroll
            for (int r = 0; r < 4; r++){
                int m = m0 + wm + i * 16 + lg * 4 + r;
                int n = n0 + wn + j * 16 + l15;
                float v = (acc[i][j][r] + bias[n]) * oscl;
                u16 o = f2bf(v);
                int b = m >> 11, t = m & (T_ - 1);
                int h = n >> 6, d = n & 63;
                if (z == 2){
                    vto[(size_t)((b * H_ + h) * HD_ + d) * T_ + t] = o;
                } else {
                    u16* dst = (z == 0) ? qo : ko;
                    dst[(size_t)((b * H_ + h) * T_ + t) * HD_ + d] = o;
                }
            }
        }
    }
}

// ---------------- output projection GEMM: 64x128 tile, single-buffer, 384 blocks ----------------
__launch_bounds__(256)
__global__ void gemm_proj(const u16* __restrict__ yb, const u16* __restrict__ wp,
                          const float* __restrict__ bp, float* __restrict__ out)
{
    const int tid  = threadIdx.x;
    const int lane = tid & 63, wave = tid >> 6;
    const int l15 = lane & 15, lg = lane >> 4;
    // XCD swizzle: nwg = 6*64 = 384, 384/8 = 48
    int flat = blockIdx.x + 6 * blockIdx.y;
    int swz  = (flat & 7) * 48 + (flat >> 3);
    const int n0 = (swz % 6) * 128;
    const int m0 = (swz / 6) * 64;

    __shared__ __align__(16) u16 lds_a[64 * 64];
    __shared__ __align__(16) u16 lds_b[128 * 64];

    fx4 acc[2][4];
    #pragma unroll
    for (int i = 0; i < 2; i++)
        #pragma unroll
        for (int j = 0; j < 4; j++) acc[i][j] = (fx4)0.0f;

    const int wm = (wave >> 1) * 32, wn = (wave & 1) * 64;
    const int sx = l15 & 7;

    for (int kt = 0; kt < C_ / 64; ++kt){
        const int k0 = kt * 64;
        #pragma unroll
        for (int c = 0; c < 2; ++c){
            int unit = c * 256 + tid;
            int row = unit >> 3, col = unit & 7;
            int gcol = (col ^ (row & 7)) * 8;
            const u16* ga = yb + (size_t)(m0 + row) * C_ + k0 + gcol;
            __builtin_amdgcn_global_load_lds((const __attribute__((address_space(1))) void*)ga,
                (__attribute__((address_space(3))) void*)(lds_a + unit * 8), 16, 0, 0);
        }
        #pragma unroll
        for (int c = 0; c < 4; ++c){
            int unit = c * 256 + tid;
            int row = unit >> 3, col = unit & 7;
            int gcol = (col ^ (row & 7)) * 8;
            const u16* gb = wp + (size_t)(n0 + row) * C_ + k0 + gcol;
            __builtin_amdgcn_global_load_lds((const __attribute__((address_space(1))) void*)gb,
                (__attribute__((address_space(3))) void*)(lds_b + unit * 8), 16, 0, 0);
        }
        __syncthreads();
        #pragma unroll
        for (int ks = 0; ks < 2; ++ks){
            bf16x8 af[2], bfr[4];
            #pragma unroll
            for (int i = 0; i < 2; i++)
                af[i]  = *(const bf16x8*)&lds_a[(wm + i * 16 + l15) * 64 + (((4 * ks + lg) ^ sx) * 8)];
            #pragma unroll
            for (int j = 0; j < 4; j++)
                bfr[j] = *(const bf16x8*)&lds_b[(wn + j * 16 + l15) * 64 + (((4 * ks + lg) ^ sx) * 8)];
            #pragma unroll
            for (int i = 0; i < 2; i++)
                #pragma unroll
                for (int j = 0; j < 4; j++)
                    acc[i][j] = __builtin_amdgcn_mfma_f32_16x16x32_bf16(af[i], bfr[j], acc[i][j], 0, 0, 0);
        }
        __syncthreads();
    }

    #pragma unroll
    for (int i = 0; i < 2; i++)
        #pragma unroll
        for (int j = 0; j < 4; j++)
            #pragma unroll
            for (int r = 0; r < 4; r++){
                int m = m0 + wm + i * 16 + lg * 4 + r;
                int n = n0 + wn + j * 16 + l15;
                out[(size_t)m * C_ + n] = acc[i][j][r] + bp[n];
            }
}

// ---------------- flash attention: 2-way split-K, 256 threads, 32KB LDS ----------------
// (unchanged from round 9)
__launch_bounds__(256)
__global__ void attn(const u16* __restrict__ q, const u16* __restrict__ kmat,
                     const u16* __restrict__ vt, const u64* __restrict__ bits,
                     u16* __restrict__ y)
{
    const int tid = threadIdx.x;
    const int pr  = tid >> 7;            // pair 0..1
    const int ptid = tid & 127;
    const int w2  = (tid >> 6) & 1;      // q-half within pair
    const int lane = tid & 63;
    const int l31 = lane & 31, hi = lane >> 5;

    int flat = blockIdx.x;
    const int bh = (flat & 7) * 3 + ((flat >> 3) % 3);     // 3 heads per XCD
    const int qt = 31 - (flat >> 3) / 3;                   // heavy first
    const int b = bh / H_, h = bh % H_;
    const int qw0 = qt * 64 + 32 * w2;

    extern __shared__ __align__(16) u16 smem[];     // 32KB: [pair][K 8KB | V 8KB]
    u16* lds_k = smem + (size_t)pr * 8192;          // [64][64] swizzled (granule ^= row&7)
    u16* lds_v = lds_k + 4096;                      // [64][64] swizzled
    float* lds_ml = (float*)smem;                   // merge m/l, aliases pair0 region

    const size_t bhoff = (size_t)bh * T_ * HD_;
    const u16* kb_ = kmat + bhoff;
    const u16* vb_ = vt + bhoff;

    bf16x8 qf[4];
    {
        const u16* qrow = q + bhoff + (size_t)(qw0 + l31) * HD_ + hi * 8;
        #pragma unroll
        for (int dc = 0; dc < 4; dc++)
            qf[dc] = *(const bf16x8*)(qrow + dc * 16);
    }

    f32x16 o0 = (f32x16)0.0f, o1 = (f32x16)0.0f;
    float m_l = -1e30f, l_l = 0.0f;            // per lane, q = qw0 + l31

    const int nkt = qt + 1;
    const int nit = (nkt + NPAIR - 1) / NPAIR;
    const int qg  = qw0 + l31;
    const u64* brow = bits + (size_t)(b * T_ + qg) * NW_;

    for (int it = 0; it < nit; ++it){
        const int kt = it * NPAIR + pr;
        const bool valid = kt < nkt;
        const int kbase = kt * 64;

        if (it > 0) __syncthreads();
        if (valid){
            #pragma unroll
            for (int i = 0; i < 4; i++){
                int u = i * 128 + ptid;    // 16B unit
                int row = u >> 3, col = u & 7;
                int gcol = (col ^ (row & 7)) * 8;
                __builtin_amdgcn_global_load_lds(
                    (const __attribute__((address_space(1))) void*)(kb_ + (size_t)(kbase + row) * HD_ + gcol),
                    (__attribute__((address_space(3))) void*)(lds_k + u * 8), 16, 0, 0);
                __builtin_amdgcn_global_load_lds(
                    (const __attribute__((address_space(1))) void*)(vb_ + (size_t)row * T_ + kbase + gcol),
                    (__attribute__((address_space(3))) void*)(lds_v + u * 8), 16, 0, 0);
            }
        }
        __syncthreads();

        if (valid){
            f32x16 s0 = (f32x16)0.0f, s1 = (f32x16)0.0f;
            #pragma unroll
            for (int dc = 0; dc < 4; dc++){
                bf16x8 kf0 = *(const bf16x8*)&lds_k[(l31     ) * 64 + (((2 * dc + hi) ^ (l31 & 7)) * 8)];
                bf16x8 kf1 = *(const bf16x8*)&lds_k[(l31 + 32) * 64 + (((2 * dc + hi) ^ (l31 & 7)) * 8)];
                s0 = __builtin_amdgcn_mfma_f32_32x32x16_bf16(kf0, qf[dc], s0, 0, 0, 0);
                s1 = __builtin_amdgcn_mfma_f32_32x32x16_bf16(kf1, qf[dc], s1, 0, 0, 0);
            }

            u64 raw = brow[kt];
            int sh = qg - kbase;
            u64 vis = sh < 0 ? 0ull : (sh >= 63 ? ~0ull : ((2ull << sh) - 1ull));
            u64 masked = raw & vis;
            if (!__all(masked == ~0ull)){
                u32 mk0 = (u32)(masked >> (4 * hi));
                u32 mk1 = (u32)(masked >> (32 + 4 * hi));
                #pragma unroll
                for (int r = 0; r < 16; r++){
                    int bpos = (r & 3) + 8 * (r >> 2);
                    s0[r] = ((mk0 >> bpos) & 1u) ? s0[r] : -1e30f;
                    s1[r] = ((mk1 >> bpos) & 1u) ? s1[r] : -1e30f;
                }
            }

            float mx = -1e30f;
            #pragma unroll
            for (int r = 0; r < 16; r++){ mx = fmaxf(mx, s0[r]); mx = fmaxf(mx, s1[r]); }
            mx = fmaxf(mx, __shfl_xor(mx, 32, 64));

            if (!__all(mx <= m_l + 10.0f)){
                float mnew = fmaxf(m_l, mx);
                float al = __builtin_amdgcn_exp2f(m_l - mnew);
                m_l = mnew;
                l_l *= al;
                #pragma unroll
                for (int r = 0; r < 16; r++){
                    int ql = (r & 3) + 8 * (r >> 2) + 4 * hi;
                    float a_r = __shfl(al, ql, 64);
                    o0[r] *= a_r; o1[r] *= a_r;
                }
            }

            float rs = 0.0f;
            bf16x8 pa[2][2];
            #pragma unroll
            for (int kb = 0; kb < 2; kb++){
                u32 P[8];
                #pragma unroll
                for (int g = 0; g < 8; g++){
                    float pe0 = __builtin_amdgcn_exp2f((kb ? s1[2*g]   : s0[2*g])   - m_l);
                    float pe1 = __builtin_amdgcn_exp2f((kb ? s1[2*g+1] : s0[2*g+1]) - m_l);
                    rs += pe0 + pe1;
                    P[g] = pack_bf2(pe0, pe1);
                }
                asm volatile("v_permlane32_swap_b32 %0, %1" : "+v"(P[0]), "+v"(P[2]));
                asm volatile("v_permlane32_swap_b32 %0, %1" : "+v"(P[1]), "+v"(P[3]));
                asm volatile("v_permlane32_swap_b32 %0, %1" : "+v"(P[4]), "+v"(P[6]));
                asm volatile("v_permlane32_swap_b32 %0, %1" : "+v"(P[5]), "+v"(P[7]));
                union { u32 uw[4]; bf16x8 v; } u0, u1;
                u0.uw[0]=P[0]; u0.uw[1]=P[1]; u0.uw[2]=P[2]; u0.uw[3]=P[3];
                u1.uw[0]=P[4]; u1.uw[1]=P[5]; u1.uw[2]=P[6]; u1.uw[3]=P[7];
                pa[kb][0] = u0.v; pa[kb][1] = u1.v;
            }
            rs += __shfl_xor(rs, 32, 64);
            l_l += rs;

            #pragma unroll
            for (int kb = 0; kb < 2; kb++)
                #pragma unroll
                for (int ks = 0; ks < 2; ks++){
                    int gidx = 4 * kb + 2 * ks + hi;
                    bf16x8 vf0 = *(const bf16x8*)&lds_v[(l31     ) * 64 + ((gidx ^ (l31 & 7)) * 8)];
                    bf16x8 vf1 = *(const bf16x8*)&lds_v[(l31 + 32) * 64 + ((gidx ^ (l31 & 7)) * 8)];
                    o0 = __builtin_amdgcn_mfma_f32_32x32x16_bf16(pa[kb][ks], vf0, o0, 0, 0, 0);
                    o1 = __builtin_amdgcn_mfma_f32_32x32x16_bf16(pa[kb][ks], vf1, o1, 0, 0, 0);
                }
        }
    }

    __syncthreads();
    {
        const int qrow = w2 * 32 + l31;
        if (hi == 0){
            lds_ml[(pr * 2 + 0) * 64 + qrow] = m_l;
            lds_ml[(pr * 2 + 1) * 64 + qrow] = l_l;
        }
        if (pr != 0){
            float* Od = (float*)(smem + (size_t)pr * 8192);
            #pragma unroll
            for (int r = 0; r < 16; r++){
                int ql = (r & 3) + 8 * (r >> 2) + 4 * hi;
                int row = w2 * 32 + ql;
                Od[row * 64 + l31]      = o0[r];
                Od[row * 64 + 32 + l31] = o1[r];
            }
        }
    }
    __syncthreads();

    if (pr == 0){
        const int qrow = w2 * 32 + l31;
        float mvals[NPAIR], lvals[NPAIR];
        mvals[0] = m_l; lvals[0] = l_l;
        #pragma unroll
        for (int p = 1; p < NPAIR; p++){
            mvals[p] = lds_ml[(p * 2 + 0) * 64 + qrow];
            lvals[p] = lds_ml[(p * 2 + 1) * 64 + qrow];
        }
        float mm = mvals[0];
        #pragma unroll
        for (int p = 1; p < NPAIR; p++) mm = fmaxf(mm, mvals[p]);
        float a[NPAIR], ltot = 0.0f;
        #pragma unroll
        for (int p = 0; p < NPAIR; p++){
            a[p] = __builtin_amdgcn_exp2f(mvals[p] - mm);
            ltot += lvals[p] * a[p];
        }
        float inv = 1.0f / ltot;

        #pragma unroll
        for (int r = 0; r < 16; r++){
            int ql = (r & 3) + 8 * (r >> 2) + 4 * hi;
            int row = w2 * 32 + ql;
            float a0r = __shfl(a[0], ql, 64);
            float v0 = o0[r] * a0r;
            float v1 = o1[r] * a0r;
            #pragma unroll
            for (int p = 1; p < NPAIR; p++){
                float apr = __shfl(a[p], ql, 64);
                const float* Od = (const float*)(smem + (size_t)p * 8192);
                v0 += Od[row * 64 + l31]      * apr;
                v1 += Od[row * 64 + 32 + l31] * apr;
            }
            float ivr = __shfl(inv, ql, 64);
            int trow = qt * 64 + row;
            u16* yr = y + (size_t)(b * T_ + trow) * C_ + h * HD_;
            yr[l31]      = f2bf(v0 * ivr);
            yr[32 + l31] = f2bf(v1 * ivr);
        }
    }
}

extern "C" void kernel_launch(void* const* d_in, const int* in_sizes, int n_in,
                              void* d_out, int out_size, void* d_ws, size_t ws_size,
                              hipStream_t stream)
{
    const float* x    = (const float*)d_in[0];
    const float* mask = (const float*)d_in[1];
    const float* Wq   = (const float*)d_in[2];
    const float* bq   = (const float*)d_in[3];
    const float* Wk   = (const float*)d_in[4];
    const float* bk   = (const float*)d_in[5];
    const float* Wv   = (const float*)d_in[6];
    const float* bv   = (const float*)d_in[7];
    const float* Wp   = (const float*)d_in[8];
    const float* bp   = (const float*)d_in[9];
    float* out = (float*)d_out;

    char* p = (char*)d_ws;
    u16* xb   = (u16*)p; p += (size_t)M_ * C_ * 2;
    u16* wqkv = (u16*)p; p += (size_t)4 * C_ * C_ * 2;
    u16* qo   = (u16*)p; p += (size_t)M_ * C_ * 2;       // [B,H,T,64] (pre-scaled)
    u16* ko   = (u16*)p; p += (size_t)M_ * C_ * 2;       // [B,H,T,64]
    u16* vto  = (u16*)p; p += (size_t)M_ * C_ * 2;       // [B,H,64,T]
    u16* yb   = (u16*)p; p += (size_t)M_ * C_ * 2;       // attn out bf16
    u64* bits = (u64*)p; p += (size_t)B_ * T_ * NW_ * 8;

    prep<<<dim3(PREP_XBLK + PREP_WBLK + PREP_MBLK), 256, 0, stream>>>(
        x, Wq, Wk, Wv, Wp, mask, xb, wqkv, bits);

    gemm_qkv<<<dim3(C_ / 128, M_ / 64, 3), 256, 0, stream>>>(
        xb, wqkv, bq, bk, bv, qo, ko, vto);

    attn<<<dim3((T_ / 64) * B_ * H_), 256, NPAIR * 8192 * sizeof(u16), stream>>>(
        qo, ko, vto, bits, yb);

    gemm_proj<<<dim3(C_ / 128, M_ / 64), 256, 0, stream>>>(yb, wqkv + (size_t)3 * C_ * C_, bp, out);
}